// Round 4
// baseline (15777.570 us; speedup 1.0000x reference)
//
#include <hip/hip_runtime.h>
#include <hip/hip_bf16.h>
#include <hip/hip_fp16.h>

typedef unsigned int u32;
typedef unsigned short u16;
typedef short s16x8 __attribute__((ext_vector_type(8)));
typedef float f32x4 __attribute__((ext_vector_type(4)));
typedef _Float16 f16x2 __attribute__((ext_vector_type(2)));

#define T_STEPS 256

// ---------------- helpers ----------------
__device__ __forceinline__ u16 f2bu(float f) {
  return __bfloat16_as_ushort(__float2bfloat16(f));
}
__device__ __forceinline__ float fast_tanh(float x) {
  float ax = fabsf(x);
  float e = __expf(-2.f * ax);
  float r = 1.f - 2.f * e / (1.f + e);
  return copysignf(r, x);
}
__device__ __forceinline__ __half2 bch2(u32 v) {
  return __builtin_bit_cast(__half2, v);
}
__device__ __forceinline__ void gload_lds16(const void* g, void* l) {
  __builtin_amdgcn_global_load_lds((const __attribute__((address_space(1))) u32*)g,
                                   (__attribute__((address_space(3))) u32*)l, 16, 0, 0);
}

// ---------------- x f32 -> bf16 ----------------
__global__ void k_cvt_bf16(const float* __restrict__ in, u16* __restrict__ out, int n4) {
  int i = blockIdx.x * blockDim.x + threadIdx.x;
  if (i >= n4) return;
  const float4 v = ((const float4*)in)[i];
  ushort4 o;
  o.x = f2bu(v.x); o.y = f2bu(v.y); o.z = f2bu(v.z); o.w = f2bu(v.w);
  ((ushort4*)out)[i] = o;
}

// ---------------- weight prep (per layer) ----------------
// BcatT [1024][512] bf16 (x-proj weights, transposed)
// WhoT  [512][512]  bf16 (h-part of Wo, transposed)
// Wpack [4 q][64 p][512 j] f16x2: for thread j of WG q: pair p covers
//   k0 = (j&3)*128 + 2p, column C = q*128 + 16*(j>>6) + ((j>>2)&15).
__global__ void k_prep_w(const float* __restrict__ Wh, const float* __restrict__ Wo,
                         u16* __restrict__ BcatT, u16* __restrict__ WhoT,
                         u32* __restrict__ Wpack) {
  int idx = blockIdx.x * 256 + threadIdx.x;
  if (idx < 1024 * 512) {
    int n = idx >> 9, k = idx & 511;
    float v = (n < 512) ? Wh[k * 512 + n] : Wo[k * 512 + (n - 512)];
    BcatT[idx] = f2bu(v);
  } else if (idx < 1024 * 512 + 512 * 512) {
    int t = idx - 1024 * 512;
    int n = t >> 9, k = t & 511;
    WhoT[t] = f2bu(Wo[(512 + k) * 512 + n]);
  } else {
    int t = idx - (1024 * 512 + 512 * 512);
    int q = t >> 15, rem = t & 32767;
    int p = rem >> 9, j = rem & 511;
    int ks = j & 3;
    int C = q * 128 + 16 * (j >> 6) + ((j >> 2) & 15);
    int k0 = ks * 128 + 2 * p;
    u16 a = __half_as_ushort(__float2half(Wh[(512 + k0) * 512 + C]));
    u16 b = __half_as_ushort(__float2half(Wh[(512 + k0 + 1) * 512 + C]));
    Wpack[t] = (u32)a | ((u32)b << 16);
  }
}

// ---------------- bf16 MFMA GEMM: C[M x N] = A[M x 512] * BT[N x 512]^T ----------------
template <int MODE>
__global__ __launch_bounds__(256) void k_gemm(
    const u16* __restrict__ A, const u16* __restrict__ BT, int NX,
    __half* __restrict__ outH, u16* __restrict__ outB, float* __restrict__ outF,
    const __half* __restrict__ Uo, const float* __restrict__ biasH,
    const float* __restrict__ biasO) {
  __shared__ __align__(16) u16 As[128 * 64], Bs[128 * 64];
  const int bid = blockIdx.x;
  const int bn = bid % NX, bm = bid / NX;
  const int m0 = bm * 128, n0 = bn * 128;
  const int tid = threadIdx.x, w = tid >> 6, l = tid & 63;
  const int l15 = l & 15, lk = (l >> 4) << 3;
  f32x4 acc[4][4] = {};
  for (int kt = 0; kt < 8; ++kt) {
    const int k0 = kt * 64;
#pragma unroll
    for (int i = 0; i < 4; ++i) {
      int idx = w * 4 + i;
      int ob = idx * 1024 + l * 16;
      int row = ob >> 7, cb = ob & 127;
      int scb = cb ^ ((row & 7) << 4);
      gload_lds16((const char*)A + (size_t)(m0 + row) * 1024 + k0 * 2 + scb,
                  (char*)As + idx * 1024);
      gload_lds16((const char*)BT + (size_t)(n0 + row) * 1024 + k0 * 2 + scb,
                  (char*)Bs + idx * 1024);
    }
    __syncthreads();
    const int wr = (w >> 1) * 64, wc = (w & 1) * 64;
#pragma unroll
    for (int kk = 0; kk < 2; ++kk) {
      s16x8 af[4], bfr[4];
      const int kb = (kk * 32 + lk) * 2;
#pragma unroll
      for (int i = 0; i < 4; ++i) {
        int ar = wr + i * 16 + l15;
        af[i] = *(const s16x8*)((const char*)As + ar * 128 + (kb ^ ((ar & 7) << 4)));
        int br = wc + i * 16 + l15;
        bfr[i] = *(const s16x8*)((const char*)Bs + br * 128 + (kb ^ ((br & 7) << 4)));
      }
#pragma unroll
      for (int i = 0; i < 4; ++i)
#pragma unroll
        for (int jj = 0; jj < 4; ++jj)
          acc[i][jj] = __builtin_amdgcn_mfma_f32_16x16x32_bf16(af[i], bfr[jj], acc[i][jj], 0, 0, 0);
    }
    __syncthreads();
  }
#pragma unroll
  for (int i = 0; i < 4; ++i)
#pragma unroll
    for (int jj = 0; jj < 4; ++jj)
#pragma unroll
      for (int rr = 0; rr < 4; ++rr) {
        int row = m0 + (w >> 1) * 64 + i * 16 + ((l >> 4) << 2) + rr;
        int col = n0 + (w & 1) * 64 + jj * 16 + l15;
        float v = acc[i][jj][rr];
        if (MODE == 0) {
          float bsv = (col < 512) ? biasH[col] : biasO[col - 512];
          outH[(size_t)row * 1024 + col] = __float2half(v + bsv);
        } else {
          float o = fast_tanh(v + __half2float(Uo[(size_t)row * 1024 + col]));
          if (MODE == 1) outB[(size_t)row * 512 + col] = f2bu(o);
          else           outF[(size_t)row * 512 + col] = o;
        }
      }
}

// ---------------- recurrent scan: 4 WGs per batch row, 256 WGs total ----------------
// WG (b,q) computes cols [128q,128q+128) of row b. Thread = (col, k-slice of 128).
// 64 weight pairs fully in VGPRs. h exchanged via L2 (double-buffered hstate,
// per-row release/acquire counter). bid%8 keeps a row's 4 WGs on one XCD.
__global__ __launch_bounds__(512) void k_scan2(
    const u32* __restrict__ Wq, const __half* __restrict__ Uh,
    const float* __restrict__ h0, u16* __restrict__ Hseq,
    __half* __restrict__ hstate, u32* __restrict__ cnt) {
  const int bid = blockIdx.x;
  const int q = (bid >> 3) & 3;              // same-XCD grouping: bid%8 = b%8
  const int b = (bid & 7) + 8 * (bid >> 5);
  const int j = threadIdx.x;
  const int ks = j & 3;
  const int C = q * 128 + 16 * (j >> 6) + ((j >> 2) & 15);
  u32 w[64];
  {
    const u32* wp = Wq + (size_t)q * 32768 + j;
#pragma unroll
    for (int p = 0; p < 64; ++p) w[p] = wp[p * 512];
  }
  float hcur = h0 ? h0[b * 512 + C] : 0.f;
  if (ks == 0) hstate[(size_t)b * 512 + C] = __float2half(hcur);  // parity 0
  __syncthreads();
  if (j == 0) __hip_atomic_fetch_add(cnt + b, 1u, __ATOMIC_RELEASE, __HIP_MEMORY_SCOPE_AGENT);
  const size_t r0 = (size_t)b * T_STEPS;
  float u_cur = __half2float(Uh[r0 * 1024 + C]);
  u32 target = 4;
  for (int t = 0; t < T_STEPS; ++t) {
    const size_t r = r0 + t;
    if (ks == 0) Hseq[r * 512 + C] = f2bu(hcur);   // h_in at step t
    float u_nxt = (t + 1 < T_STEPS) ? __half2float(Uh[(r + 1) * 1024 + C]) : 0.f;
    while (__hip_atomic_load(cnt + b, __ATOMIC_ACQUIRE, __HIP_MEMORY_SCOPE_AGENT) < target) {}
    const uint4* hs = (const uint4*)(hstate + (((size_t)(t & 1) * 64 + b) * 512 + ks * 128));
    __half2 a0 = __float2half2_rn(0.f), a1 = a0, a2 = a0, a3 = a0;
#pragma unroll
    for (int i = 0; i < 16; ++i) {
      uint4 hv = hs[i];
      a0 = __hfma2(bch2(w[4 * i + 0]), bch2(hv.x), a0);
      a1 = __hfma2(bch2(w[4 * i + 1]), bch2(hv.y), a1);
      a2 = __hfma2(bch2(w[4 * i + 2]), bch2(hv.z), a2);
      a3 = __hfma2(bch2(w[4 * i + 3]), bch2(hv.w), a3);
    }
    float part = __low2float(a0) + __high2float(a0) + __low2float(a1) + __high2float(a1)
               + __low2float(a2) + __high2float(a2) + __low2float(a3) + __high2float(a3);
    part += __shfl_xor(part, 1);
    part += __shfl_xor(part, 2);
    float hn = fast_tanh(part + u_cur);
    if (ks == 0) hstate[((size_t)((t + 1) & 1) * 64 + b) * 512 + C] = __float2half(hn);
    __syncthreads();   // all waves' stores drained (vmcnt(0) before barrier)
    if (j == 0) __hip_atomic_fetch_add(cnt + b, 1u, __ATOMIC_RELEASE, __HIP_MEMORY_SCOPE_AGENT);
    hcur = hn; u_cur = u_nxt; target += 4;
  }
}

// ---------------- launch ----------------
extern "C" void kernel_launch(void* const* d_in, const int* in_sizes, int n_in,
                              void* d_out, int out_size, void* d_ws, size_t ws_size,
                              hipStream_t stream) {
  const float* x   = (const float*)d_in[0];
  const float* enc = (const float*)d_in[1];
  const float* Wh0 = (const float*)d_in[2];
  const float* bh0 = (const float*)d_in[3];
  const float* Wo0 = (const float*)d_in[4];
  const float* bo0 = (const float*)d_in[5];
  const float* Wh1 = (const float*)d_in[6];
  const float* bh1 = (const float*)d_in[7];
  const float* Wo1 = (const float*)d_in[8];
  const float* bo1 = (const float*)d_in[9];
  char* ws = (char*)d_ws;
  u16*    Xbf   = (u16*)(ws);
  __half* U     = (__half*)(ws + 16777216);
  u16*    Hs0   = (u16*)(ws + 16777216 + 33554432);
  u16*    Out0  = (u16*)(ws + 16777216 + 33554432 + 16777216);
  u16*    Hs1   = (u16*)(ws + 16777216 + 33554432 + 2 * 16777216);
  char*   wb    = ws + 16777216 + 33554432 + 3 * 16777216;
  u16*    Bct0  = (u16*)(wb);
  u16*    WhoT0 = (u16*)(wb + 1048576);
  u32*    Wpk0  = (u32*)(wb + 1048576 + 524288);
  u16*    Bct1  = (u16*)(wb + 1048576 + 2 * 524288);
  u16*    WhoT1 = (u16*)(wb + 2 * 1048576 + 2 * 524288);
  u32*    Wpk1  = (u32*)(wb + 2 * 1048576 + 3 * 524288);
  __half* hst   = (__half*)(wb + 2 * 1048576 + 4 * 524288);       // 2*64*512 f16 = 128KB
  u32*    cntA  = (u32*)(wb + 2 * 1048576 + 4 * 524288 + 131072); // 64 u32
  u32*    cntB  = cntA + 64;

  hipMemsetAsync(cntA, 0, 512, stream);

  k_cvt_bf16<<<8192, 256, 0, stream>>>(x, Xbf, 8388608 / 4);
  k_prep_w<<<3584, 256, 0, stream>>>(Wh0, Wo0, Bct0, WhoT0, Wpk0);
  k_prep_w<<<3584, 256, 0, stream>>>(Wh1, Wo1, Bct1, WhoT1, Wpk1);
  k_gemm<0><<<1024, 256, 0, stream>>>(Xbf, Bct0, 8, U, nullptr, nullptr, nullptr, bh0, bo0);

  {
    const u32* a0 = Wpk0; const __half* a1 = U; const float* a2 = enc;
    u16* a3 = Hs0; __half* a4 = hst; u32* a5 = cntA;
    void* args[] = {&a0, &a1, &a2, &a3, &a4, &a5};
    hipLaunchCooperativeKernel((const void*)k_scan2, dim3(256), dim3(512), args, 0, stream);
  }

  k_gemm<1><<<512, 256, 0, stream>>>(Hs0, WhoT0, 4, nullptr, Out0, nullptr, U + 512, nullptr, nullptr);
  k_gemm<0><<<1024, 256, 0, stream>>>(Out0, Bct1, 8, U, nullptr, nullptr, nullptr, bh1, bo1);

  {
    const u32* a0 = Wpk1; const __half* a1 = U; const float* a2 = nullptr;
    u16* a3 = Hs1; __half* a4 = hst; u32* a5 = cntB;
    void* args[] = {&a0, &a1, &a2, &a3, &a4, &a5};
    hipLaunchCooperativeKernel((const void*)k_scan2, dim3(256), dim3(512), args, 0, stream);
  }

  k_gemm<2><<<512, 256, 0, stream>>>(Hs1, WhoT1, 4, nullptr, nullptr, (float*)d_out, U + 512, nullptr, nullptr);
}

// Round 5
// 1109.096 us; speedup vs baseline: 14.2256x; 14.2256x over previous
//
#include <hip/hip_runtime.h>
#include <hip/hip_bf16.h>
#include <hip/hip_fp16.h>

typedef unsigned int u32;
typedef unsigned short u16;
typedef short s16x8 __attribute__((ext_vector_type(8)));
typedef float f32x4 __attribute__((ext_vector_type(4)));
typedef _Float16 f16x2 __attribute__((ext_vector_type(2)));

#define T_STEPS 256

// ---------------- helpers ----------------
__device__ __forceinline__ u16 f2bu(float f) {
  return __bfloat16_as_ushort(__float2bfloat16(f));
}
__device__ __forceinline__ float fast_tanh(float x) {
  float ax = fabsf(x);
  float e = __expf(-2.f * ax);
  float r = 1.f - 2.f * e / (1.f + e);
  return copysignf(r, x);
}
__device__ __forceinline__ __half2 bch2(u32 v) {
  return __builtin_bit_cast(__half2, v);
}
__device__ __forceinline__ void gload_lds16(const void* g, void* l) {
  __builtin_amdgcn_global_load_lds((const __attribute__((address_space(1))) u32*)g,
                                   (__attribute__((address_space(3))) u32*)l, 16, 0, 0);
}
// WG-level wait: thread 0 polls (acquire), then barrier releases the WG.
__device__ __forceinline__ void wg_wait_ge(const u32* p, u32 target) {
  if (threadIdx.x == 0) {
    while (__hip_atomic_load(p, __ATOMIC_ACQUIRE, __HIP_MEMORY_SCOPE_AGENT) < target)
      __builtin_amdgcn_s_sleep(16);
  }
  __syncthreads();
}

// ---------------- x f32 -> bf16 ----------------
__global__ void k_cvt_bf16(const float* __restrict__ in, u16* __restrict__ out, int n4) {
  int i = blockIdx.x * blockDim.x + threadIdx.x;
  if (i >= n4) return;
  const float4 v = ((const float4*)in)[i];
  ushort4 o;
  o.x = f2bu(v.x); o.y = f2bu(v.y); o.z = f2bu(v.z); o.w = f2bu(v.w);
  ((ushort4*)out)[i] = o;
}

// ---------------- weight prep (per layer, round-3 layout) ----------------
// BcatT [1024][512] bf16: x-proj weights (h|o concat), transposed
// WhoT  [512][512]  bf16: h-part of Wo, transposed
// Wpack [256 k2][512 j] f16x2: h-part of Wh, k-paired
__global__ void k_prep_w(const float* __restrict__ Wh, const float* __restrict__ Wo,
                         u16* __restrict__ BcatT, u16* __restrict__ WhoT,
                         u32* __restrict__ Wpack) {
  int idx = blockIdx.x * 256 + threadIdx.x;
  if (idx < 1024 * 512) {
    int n = idx >> 9, k = idx & 511;
    float v = (n < 512) ? Wh[k * 512 + n] : Wo[k * 512 + (n - 512)];
    BcatT[idx] = f2bu(v);
  } else if (idx < 1024 * 512 + 512 * 512) {
    int t = idx - 1024 * 512;
    int n = t >> 9, k = t & 511;
    WhoT[t] = f2bu(Wo[(512 + k) * 512 + n]);
  } else {
    int t = idx - (1024 * 512 + 512 * 512);
    int k2 = t >> 9, j = t & 511;
    u16 a = __half_as_ushort(__float2half(Wh[(512 + 2 * k2) * 512 + j]));
    u16 b = __half_as_ushort(__float2half(Wh[(512 + 2 * k2 + 1) * 512 + j]));
    Wpack[t] = (u32)a | ((u32)b << 16);
  }
}

// ---------------- bf16 MFMA GEMM (head U0, tail final) ----------------
template <int MODE>
__global__ __launch_bounds__(256) void k_gemm(
    const u16* __restrict__ A, const u16* __restrict__ BT, int NX,
    __half* __restrict__ outH, u16* __restrict__ outB, float* __restrict__ outF,
    const __half* __restrict__ Uo, const float* __restrict__ biasH,
    const float* __restrict__ biasO) {
  __shared__ __align__(16) u16 As[128 * 64], Bs[128 * 64];
  const int bid = blockIdx.x;
  const int bn = bid % NX, bm = bid / NX;
  const int m0 = bm * 128, n0 = bn * 128;
  const int tid = threadIdx.x, w = tid >> 6, l = tid & 63;
  const int l15 = l & 15, lk = (l >> 4) << 3;
  f32x4 acc[4][4] = {};
  for (int kt = 0; kt < 8; ++kt) {
    const int k0 = kt * 64;
#pragma unroll
    for (int i = 0; i < 4; ++i) {
      int idx = w * 4 + i;
      int ob = idx * 1024 + l * 16;
      int row = ob >> 7, cb = ob & 127;
      int scb = cb ^ ((row & 7) << 4);
      gload_lds16((const char*)A + (size_t)(m0 + row) * 1024 + k0 * 2 + scb,
                  (char*)As + idx * 1024);
      gload_lds16((const char*)BT + (size_t)(n0 + row) * 1024 + k0 * 2 + scb,
                  (char*)Bs + idx * 1024);
    }
    __syncthreads();
    const int wr = (w >> 1) * 64, wc = (w & 1) * 64;
#pragma unroll
    for (int kk = 0; kk < 2; ++kk) {
      s16x8 af[4], bfr[4];
      const int kb = (kk * 32 + lk) * 2;
#pragma unroll
      for (int i = 0; i < 4; ++i) {
        int ar = wr + i * 16 + l15;
        af[i] = *(const s16x8*)((const char*)As + ar * 128 + (kb ^ ((ar & 7) << 4)));
        int br = wc + i * 16 + l15;
        bfr[i] = *(const s16x8*)((const char*)Bs + br * 128 + (kb ^ ((br & 7) << 4)));
      }
#pragma unroll
      for (int i = 0; i < 4; ++i)
#pragma unroll
        for (int jj = 0; jj < 4; ++jj)
          acc[i][jj] = __builtin_amdgcn_mfma_f32_16x16x32_bf16(af[i], bfr[jj], acc[i][jj], 0, 0, 0);
    }
    __syncthreads();
  }
#pragma unroll
  for (int i = 0; i < 4; ++i)
#pragma unroll
    for (int jj = 0; jj < 4; ++jj)
#pragma unroll
      for (int rr = 0; rr < 4; ++rr) {
        int row = m0 + (w >> 1) * 64 + i * 16 + ((l >> 4) << 2) + rr;
        int col = n0 + (w & 1) * 64 + jj * 16 + l15;
        float v = acc[i][jj][rr];
        if (MODE == 0) {
          float bsv = (col < 512) ? biasH[col] : biasO[col - 512];
          outH[(size_t)row * 1024 + col] = __float2half(v + bsv);
        } else {
          float o = fast_tanh(v + __half2float(Uo[(size_t)row * 1024 + col]));
          if (MODE == 1) outB[(size_t)row * 512 + col] = f2bu(o);
          else           outF[(size_t)row * 512 + col] = o;
        }
      }
}

// ---------------- scan role (round-3 inner loop + block-gated sync) ----------------
#define REG_P 192
#define LDS_GRP 16
#define SCAN_LDS_BYTES (LDS_GRP * 8192 + 2048)

__device__ void scan_role(u32* smem, const u32* __restrict__ Wpack,
                          const __half* __restrict__ Uh, const float* __restrict__ h0,
                          u16* __restrict__ Hseq, int b,
                          u32* rel, const u32* pollv) {
  u32* Wl = smem;
  __half* hb = (__half*)(smem + LDS_GRP * 2048);
  const int j = threadIdx.x;
  u32 wreg[REG_P];
#pragma unroll
  for (int p = 0; p < REG_P; ++p) wreg[p] = Wpack[p * 512 + j];
#pragma unroll
  for (int g = 0; g < LDS_GRP; ++g)
#pragma unroll
    for (int q = 0; q < 4; ++q)
      Wl[g * 2048 + j * 4 + q] = Wpack[(REG_P + 4 * g + q) * 512 + j];
  float h = h0 ? h0[b * 512 + j] : 0.f;
  hb[j] = __float2half(h);
  __syncthreads();
  const size_t r0 = (size_t)b * T_STEPS;
  float u_cur = 0.f;
  for (int t = 0; t < T_STEPS; ++t) {
    const size_t r = r0 + t;
    if ((t & 31) == 0) {
      if (pollv) wg_wait_ge(pollv + (size_t)(t >> 5) * 16, 8u);
      if (rel && t && j == 0)
        __hip_atomic_store(rel, (u32)t, __ATOMIC_RELEASE, __HIP_MEMORY_SCOPE_AGENT);
      u_cur = __half2float(Uh[r * 1024 + j]);     // fresh load at block start
    }
    Hseq[r * 512 + j] = f2bu(h);                  // h_in at step t
    float u_nxt = ((t & 31) != 31) ? __half2float(Uh[(r + 1) * 1024 + j]) : 0.f;
    const uint4* h4 = (const uint4*)(hb + (t & 1) * 512);
    __half2 a0 = __float2half2_rn(0.f), a1 = a0, a2 = a0, a3 = a0;
#pragma unroll
    for (int g = 0; g < 48; ++g) {
      uint4 hv = h4[g];
      a0 = __hfma2(bch2(wreg[4 * g + 0]), bch2(hv.x), a0);
      a1 = __hfma2(bch2(wreg[4 * g + 1]), bch2(hv.y), a1);
      a2 = __hfma2(bch2(wreg[4 * g + 2]), bch2(hv.z), a2);
      a3 = __hfma2(bch2(wreg[4 * g + 3]), bch2(hv.w), a3);
    }
#pragma unroll
    for (int g = 0; g < LDS_GRP; ++g) {
      uint4 hv = h4[48 + g];
      uint4 wv = *(const uint4*)&Wl[g * 2048 + j * 4];
      a0 = __hfma2(bch2(wv.x), bch2(hv.x), a0);
      a1 = __hfma2(bch2(wv.y), bch2(hv.y), a1);
      a2 = __hfma2(bch2(wv.z), bch2(hv.z), a2);
      a3 = __hfma2(bch2(wv.w), bch2(hv.w), a3);
    }
    float acc = u_cur;
    acc += __low2float(a0) + __high2float(a0);
    acc += __low2float(a1) + __high2float(a1);
    acc += __low2float(a2) + __high2float(a2);
    acc += __low2float(a3) + __high2float(a3);
    float hn = fast_tanh(acc);
    hb[((t + 1) & 1) * 512 + j] = __float2half(hn);
    h = hn;
    u_cur = u_nxt;
    __syncthreads();
  }
  if (rel && j == 0)
    __hip_atomic_store(rel, 256u, __ATOMIC_RELEASE, __HIP_MEMORY_SCOPE_AGENT);
}

// ---------------- helper role: 32x128 MFMA tiles, direct-global frags ----------------
// Queue per tb-block: 256 out0 tiles then 512 U1 tiles; 8 blocks -> 6144 items.
__device__ void helper_role(int hid, __half* __restrict__ U,
                            const u16* __restrict__ Hs0, u16* __restrict__ Out0,
                            const u16* __restrict__ WhoT0, const u16* __restrict__ Bct1,
                            const float* __restrict__ bh1, const float* __restrict__ bo1,
                            u32* prog0, u32* o0done, u32* u1done) {
  const int tid = threadIdx.x;
  const int w = tid >> 6, l = tid & 63;
  const int wr = w >> 2, wc = w & 3, l15 = l & 15, lk8 = (l >> 4) * 8;
  for (int id = hid; id < 6144; id += 128) {
    const int tb = id / 768, loc = id % 768;
    if (loc < 256) {
      // out0 tile: rows [b*256+tb*32, +32), cols [cq*128, +128)
      const int b = loc >> 2, cq = loc & 3;
      wg_wait_ge(prog0 + (size_t)b * 16, (u32)(32 * (tb + 1)));
      const int r0 = b * 256 + tb * 32, c0 = cq * 128;
      const int arow = r0 + wr * 16 + l15;
      const int bc0 = c0 + wc * 32 + l15, bc1 = bc0 + 16;
      f32x4 a0 = {}, a1 = {};
#pragma unroll
      for (int k0 = 0; k0 < 512; k0 += 32) {
        s16x8 av = *(const s16x8*)&Hs0[(size_t)arow * 512 + k0 + lk8];
        s16x8 b0 = *(const s16x8*)&WhoT0[(size_t)bc0 * 512 + k0 + lk8];
        s16x8 b1 = *(const s16x8*)&WhoT0[(size_t)bc1 * 512 + k0 + lk8];
        a0 = __builtin_amdgcn_mfma_f32_16x16x32_bf16(av, b0, a0, 0, 0, 0);
        a1 = __builtin_amdgcn_mfma_f32_16x16x32_bf16(av, b1, a1, 0, 0, 0);
      }
#pragma unroll
      for (int rr = 0; rr < 4; ++rr) {
        int row = r0 + wr * 16 + (l >> 4) * 4 + rr;
        int cA = c0 + wc * 32 + l15, cB = cA + 16;
        float vA = fast_tanh(a0[rr] + __half2float(U[(size_t)row * 1024 + 512 + cA]));
        float vB = fast_tanh(a1[rr] + __half2float(U[(size_t)row * 1024 + 512 + cB]));
        Out0[(size_t)row * 512 + cA] = f2bu(vA);
        Out0[(size_t)row * 512 + cB] = f2bu(vB);
      }
      __syncthreads();
      if (tid == 0)
        __hip_atomic_fetch_add(o0done + ((size_t)b * 8 + tb) * 16, 1u,
                               __ATOMIC_RELEASE, __HIP_MEMORY_SCOPE_AGENT);
    } else {
      // U1 tile: rows [b*256+tb*32, +32), out cols [cc*128, +128) of 1024
      const int loc2 = loc - 256;
      const int b = loc2 >> 3, cc = loc2 & 7;
      wg_wait_ge(o0done + ((size_t)b * 8 + tb) * 16, 4u);
      const int r0 = b * 256 + tb * 32, c0 = cc * 128;
      const int arow = r0 + wr * 16 + l15;
      const int bc0 = c0 + wc * 32 + l15, bc1 = bc0 + 16;
      f32x4 a0 = {}, a1 = {};
#pragma unroll
      for (int k0 = 0; k0 < 512; k0 += 32) {
        s16x8 av = *(const s16x8*)&Out0[(size_t)arow * 512 + k0 + lk8];
        s16x8 b0 = *(const s16x8*)&Bct1[(size_t)bc0 * 512 + k0 + lk8];
        s16x8 b1 = *(const s16x8*)&Bct1[(size_t)bc1 * 512 + k0 + lk8];
        a0 = __builtin_amdgcn_mfma_f32_16x16x32_bf16(av, b0, a0, 0, 0, 0);
        a1 = __builtin_amdgcn_mfma_f32_16x16x32_bf16(av, b1, a1, 0, 0, 0);
      }
#pragma unroll
      for (int rr = 0; rr < 4; ++rr) {
        int row = r0 + wr * 16 + (l >> 4) * 4 + rr;
        int cA = c0 + wc * 32 + l15, cB = cA + 16;
        float bA = (cA < 512) ? bh1[cA] : bo1[cA - 512];
        float bB = (cB < 512) ? bh1[cB] : bo1[cB - 512];
        U[(size_t)row * 1024 + cA] = __float2half(a0[rr] + bA);
        U[(size_t)row * 1024 + cB] = __float2half(a1[rr] + bB);
      }
      __syncthreads();
      if (tid == 0)
        __hip_atomic_fetch_add(u1done + ((size_t)b * 8 + tb) * 16, 1u,
                               __ATOMIC_RELEASE, __HIP_MEMORY_SCOPE_AGENT);
    }
  }
}

// ---------------- mega kernel: scan0 || helpers(out0,U1) || scan1 ----------------
__global__ __launch_bounds__(512, 2) void k_mega(
    const u32* __restrict__ Wpk0, const u32* __restrict__ Wpk1,
    __half* __restrict__ U, const float* __restrict__ enc,
    u16* __restrict__ Hs0, u16* __restrict__ Hs1, u16* __restrict__ Out0,
    const u16* __restrict__ WhoT0, const u16* __restrict__ Bct1,
    const float* __restrict__ bh1, const float* __restrict__ bo1,
    u32* prog0, u32* o0done, u32* u1done) {
  extern __shared__ __align__(16) u32 smem[];
  const int wg = blockIdx.x;
  if (wg < 64) {
    scan_role(smem, Wpk0, U, enc, Hs0, wg, prog0 + (size_t)wg * 16, nullptr);
  } else if (wg < 128) {
    const int b = wg - 64;
    scan_role(smem, Wpk1, U, nullptr, Hs1, b, nullptr, u1done + (size_t)b * 8 * 16);
  } else {
    helper_role(wg - 128, U, Hs0, Out0, WhoT0, Bct1, bh1, bo1, prog0, o0done, u1done);
  }
}

// ---------------- launch ----------------
extern "C" void kernel_launch(void* const* d_in, const int* in_sizes, int n_in,
                              void* d_out, int out_size, void* d_ws, size_t ws_size,
                              hipStream_t stream) {
  const float* x   = (const float*)d_in[0];
  const float* enc = (const float*)d_in[1];
  const float* Wh0 = (const float*)d_in[2];
  const float* bh0 = (const float*)d_in[3];
  const float* Wo0 = (const float*)d_in[4];
  const float* bo0 = (const float*)d_in[5];
  const float* Wh1 = (const float*)d_in[6];
  const float* bh1 = (const float*)d_in[7];
  const float* Wo1 = (const float*)d_in[8];
  const float* bo1 = (const float*)d_in[9];
  char* ws = (char*)d_ws;
  // ws layout: U 32MB | Hs0 16MB | Hs1 16MB | XO 16MB (Xbf head / Out0 mega) | weights 4MB | counters
  __half* U    = (__half*)(ws);
  u16*    Hs0  = (u16*)(ws + 33554432);
  u16*    Hs1  = (u16*)(ws + 33554432 + 16777216);
  u16*    XO   = (u16*)(ws + 33554432 + 2 * 16777216);
  char*   wb   = ws + 33554432 + 3 * 16777216;
  u16*    Bct0  = (u16*)(wb);
  u16*    WhoT0 = (u16*)(wb + 1048576);
  u32*    Wpk0  = (u32*)(wb + 1048576 + 524288);
  u16*    Bct1  = (u16*)(wb + 1048576 + 2 * 524288);
  u16*    WhoT1 = (u16*)(wb + 2 * 1048576 + 2 * 524288);
  u32*    Wpk1  = (u32*)(wb + 2 * 1048576 + 3 * 524288);
  u32*    cnt   = (u32*)(wb + 2 * 1048576 + 4 * 524288);
  u32*    prog0  = cnt;            // 64 x 16 u32 (padded)
  u32*    o0done = cnt + 1024;     // 512 x 16 u32
  u32*    u1done = cnt + 1024 + 8192;

  (void)hipFuncSetAttribute((const void*)k_mega,
                            hipFuncAttributeMaxDynamicSharedMemorySize,
                            SCAN_LDS_BYTES);

  hipMemsetAsync(cnt, 0, (1024 + 2 * 8192) * 4, stream);
  k_cvt_bf16<<<8192, 256, 0, stream>>>(x, XO, 8388608 / 4);
  k_prep_w<<<3584, 256, 0, stream>>>(Wh0, Wo0, Bct0, WhoT0, Wpk0);
  k_prep_w<<<3584, 256, 0, stream>>>(Wh1, Wo1, Bct1, WhoT1, Wpk1);
  // U = [x-proj h | x-proj o] + biases, layer 0
  k_gemm<0><<<1024, 256, 0, stream>>>(XO, Bct0, 8, U, nullptr, nullptr, nullptr, bh0, bo0);

  {
    const u32* a0 = Wpk0; const u32* a1 = Wpk1; __half* a2 = U;
    const float* a3 = enc; u16* a4 = Hs0; u16* a5 = Hs1; u16* a6 = XO;
    const u16* a7 = WhoT0; const u16* a8 = Bct1;
    const float* a9 = bh1; const float* a10 = bo1;
    u32* a11 = prog0; u32* a12 = o0done; u32* a13 = u1done;
    void* args[] = {&a0, &a1, &a2, &a3, &a4, &a5, &a6, &a7, &a8, &a9, &a10, &a11, &a12, &a13};
    hipLaunchCooperativeKernel((const void*)k_mega, dim3(256), dim3(512), args,
                               SCAN_LDS_BYTES, stream);
  }

  // final: out = tanh(U1_o + Hs1 @ Who1) -> [B,T,D] f32
  k_gemm<2><<<512, 256, 0, stream>>>(Hs1, WhoT1, 4, nullptr, nullptr, (float*)d_out,
                                     U + 512, nullptr, nullptr);
}